// Round 1
// baseline (188.964 us; speedup 1.0000x reference)
//
#include <hip/hip_runtime.h>
#include <math.h>

#define HH 128
#define WW 128
#define MAP_ELEMS (HH * WW)      // 16384
#define BLOCK 256
#define N4 (MAP_ELEMS / 4)       // 4096 float4 per map
#define ITERS (N4 / BLOCK)       // 16 float4 per thread

__global__ __launch_bounds__(BLOCK) void spatial_argmax2d_kernel(
    const float* __restrict__ in, float* __restrict__ out) {
    const int map = blockIdx.x;  // b*N + n
    const float* __restrict__ base = in + (size_t)map * MAP_ELEMS;
    const float4* __restrict__ base4 = (const float4*)base;
    const int tid = threadIdx.x;

    // Two independent (value, float4-index) chains to shorten the dependent
    // compare chain behind each returning load. Per float4 we only track the
    // max of its 4 lanes (v_max tree) + which float4 it was; the sub-index
    // within the winning float4 is resolved ONCE per block at the end.
    float bvA = -INFINITY, bvB = -INFINITY;
    int biA = 0x7fffffff, biB = 0x7fffffff;

#pragma unroll
    for (int k = 0; k < ITERS; k += 2) {
        const int ia = k * BLOCK + tid;
        const int ib = (k + 1) * BLOCK + tid;
        const float4 va = base4[ia];
        const float4 vb = base4[ib];
        const float ma = fmaxf(fmaxf(va.x, va.y), fmaxf(va.z, va.w));
        const float mb = fmaxf(fmaxf(vb.x, vb.y), fmaxf(vb.z, vb.w));
        // Strict '>' keeps the FIRST float4 achieving the max within each chain
        // (indices ascend monotonically per chain).
        if (ma > bvA) { bvA = ma; biA = ia; }
        if (mb > bvB) { bvB = mb; biB = ib; }
    }

    // Merge chains. Chain indices interleave, so on a value tie the smaller
    // float4-index is the earlier occurrence.
    float best_v = bvA;
    int best_i4 = biA;
    if (bvB > best_v || (bvB == best_v && biB < best_i4)) {
        best_v = bvB; best_i4 = biB;
    }

    // 64-lane wave reduction (wavefront = 64 on CDNA). Tie-break on smaller
    // float4-index: element index = i4*4 + j, and distinct threads never share
    // an i4, so i4 ordering == element-index ordering across threads.
#pragma unroll
    for (int off = 32; off > 0; off >>= 1) {
        const float v2 = __shfl_down(best_v, off);
        const int   i2 = __shfl_down(best_i4, off);
        if (v2 > best_v || (v2 == best_v && i2 < best_i4)) {
            best_v = v2; best_i4 = i2;
        }
    }

    __shared__ float sv[BLOCK / 64];
    __shared__ int   si[BLOCK / 64];
    const int wave = tid >> 6;
    if ((tid & 63) == 0) { sv[wave] = best_v; si[wave] = best_i4; }
    __syncthreads();

    if (tid == 0) {
#pragma unroll
        for (int w = 1; w < BLOCK / 64; ++w) {
            if (sv[w] > best_v || (sv[w] == best_v && si[w] < best_i4)) {
                best_v = sv[w]; best_i4 = si[w];
            }
        }

        // Resolve the sub-index within the winning float4: first j with
        // v[j] == best_v (descending-order overwrites keep the earliest).
        const float4 vw = base4[best_i4];
        int j = 3;
        if (vw.z == best_v) j = 2;
        if (vw.y == best_v) j = 1;
        if (vw.x == best_v) j = 0;
        const int best_i = best_i4 * 4 + j;

        const int y = best_i >> 7;        // / 128
        const int x = best_i & (WW - 1);  // % 128

        // Replicate padding == clamped neighbor coords.
        const float c = best_v;
        const int xl = (x > 0)      ? x - 1 : 0;
        const int xr = (x < WW - 1) ? x + 1 : WW - 1;
        const int yu = (y > 0)      ? y - 1 : 0;
        const int yd = (y < HH - 1) ? y + 1 : HH - 1;
        const float l = base[y  * WW + xl];
        const float r = base[y  * WW + xr];
        const float u = base[yu * WW + x];
        const float d = base[yd * WW + x];

        const float den_x = l - 2.0f * c + r;
        const float den_y = u - 2.0f * c + d;
        const float dx = (den_x != 0.0f) ? 0.5f * (l - r) / den_x : 0.0f;
        const float dy = (den_y != 0.0f) ? 0.5f * (u - d) / den_y : 0.0f;

        out[map * 2 + 0] = (float)x + dx;
        out[map * 2 + 1] = (float)y + dy;
    }
}

extern "C" void kernel_launch(void* const* d_in, const int* in_sizes, int n_in,
                              void* d_out, int out_size, void* d_ws, size_t ws_size,
                              hipStream_t stream) {
    const float* in = (const float*)d_in[0];
    float* out = (float*)d_out;
    const int n_maps = in_sizes[0] / MAP_ELEMS;  // B*N = 2048
    spatial_argmax2d_kernel<<<n_maps, BLOCK, 0, stream>>>(in, out);
}

// Round 6
// 175.905 us; speedup vs baseline: 1.0742x; 1.0742x over previous
//
#include <hip/hip_runtime.h>
#include <math.h>

#define HH 128
#define WW 128
#define MAP_ELEMS (HH * WW)      // 16384
#define BLOCK 256
#define N4 (MAP_ELEMS / 4)       // 4096 float4 per map
#define W4 (WW / 4)              // 32 float4 per row
#define ITERS (N4 / BLOCK)       // 16 float4 per thread

typedef float f4v __attribute__((ext_vector_type(4)));

__global__ __launch_bounds__(BLOCK) void spatial_argmax2d_kernel(
    const float* __restrict__ in, float* __restrict__ out) {
    const int map = blockIdx.x;  // b*N + n
    const float* __restrict__ base = in + (size_t)map * MAP_ELEMS;
    const float4* __restrict__ base4 = (const float4*)base;
    const f4v* __restrict__ basev = (const f4v*)base;
    const int tid = threadIdx.x;

    // Read-once stream: nontemporal loads skip L2/L3 allocation overhead.
    // Two independent (value, float4-index) chains; sub-index within the
    // winning float4 is resolved once per block in the epilogue.
    float bvA = -INFINITY, bvB = -INFINITY;
    int biA = 0x7fffffff, biB = 0x7fffffff;

#pragma unroll
    for (int k = 0; k < ITERS; k += 2) {
        const int ia = k * BLOCK + tid;
        const int ib = (k + 1) * BLOCK + tid;
        const f4v va = __builtin_nontemporal_load(basev + ia);
        const f4v vb = __builtin_nontemporal_load(basev + ib);
        const float ma = fmaxf(fmaxf(va.x, va.y), fmaxf(va.z, va.w));
        const float mb = fmaxf(fmaxf(vb.x, vb.y), fmaxf(vb.z, vb.w));
        // Strict '>' keeps the FIRST float4 achieving the max in each chain
        // (indices ascend monotonically per chain).
        if (ma > bvA) { bvA = ma; biA = ia; }
        if (mb > bvB) { bvB = mb; biB = ib; }
    }

    // Merge chains (indices interleave: smaller i4 == earlier occurrence).
    float best_v = bvA;
    int best_i4 = biA;
    if (bvB > best_v || (bvB == best_v && biB < best_i4)) {
        best_v = bvB; best_i4 = biB;
    }

    // 64-lane wave reduction; tie-break on smaller float4-index (distinct
    // threads never share an i4, so i4 order == element-index order).
#pragma unroll
    for (int off = 32; off > 0; off >>= 1) {
        const float v2 = __shfl_down(best_v, off);
        const int   i2 = __shfl_down(best_i4, off);
        if (v2 > best_v || (v2 == best_v && i2 < best_i4)) {
            best_v = v2; best_i4 = i2;
        }
    }

    __shared__ float sv[BLOCK / 64];
    __shared__ int   si[BLOCK / 64];
    const int wave = tid >> 6;
    if ((tid & 63) == 0) { sv[wave] = best_v; si[wave] = best_i4; }
    __syncthreads();

    if (tid == 0) {
#pragma unroll
        for (int w = 1; w < BLOCK / 64; ++w) {
            if (sv[w] > best_v || (sv[w] == best_v && si[w] < best_i4)) {
                best_v = sv[w]; best_i4 = si[w];
            }
        }

        // Epilogue: all 5 loads are independent of the sub-index j, so they
        // issue in parallel -> ONE miss-latency wait instead of two.
        const int c4 = best_i4 & (W4 - 1);   // float4 column
        const int y  = best_i4 >> 5;         // / 32
        const int yu = (y > 0)      ? y - 1 : 0;
        const int yd = (y < HH - 1) ? y + 1 : HH - 1;
        // Clamped scalar indices; when the winner sits on a map edge these
        // degenerate to the center element, matching replicate padding.
        const int xl = (c4 > 0)      ? c4 * 4 - 1 : 0;
        const int xr = (c4 < W4 - 1) ? c4 * 4 + 4 : WW - 1;

        const float4 vw = base4[best_i4];
        const float4 up = base4[yu * W4 + c4];
        const float4 dn = base4[yd * W4 + c4];
        const float  lf = base[y * WW + xl];
        const float  rt = base[y * WW + xr];

        // First j with vw[j] == best_v (descending overwrites keep earliest).
        int j = 3;
        if (vw.z == best_v) j = 2;
        if (vw.y == best_v) j = 1;
        if (vw.x == best_v) j = 0;
        const int x = c4 * 4 + j;

        const float c = best_v;
        const float u = (j == 0) ? up.x : (j == 1) ? up.y : (j == 2) ? up.z : up.w;
        const float d = (j == 0) ? dn.x : (j == 1) ? dn.y : (j == 2) ? dn.z : dn.w;
        // In-float4 neighbors come from registers; boundary ones from lf/rt
        // (whose clamped indices already implement replicate padding).
        const float l = (j > 0) ? ((j == 1) ? vw.x : (j == 2) ? vw.y : vw.z) : lf;
        const float r = (j < 3) ? ((j == 0) ? vw.y : (j == 1) ? vw.z : vw.w) : rt;

        const float den_x = l - 2.0f * c + r;
        const float den_y = u - 2.0f * c + d;
        const float dx = (den_x != 0.0f) ? 0.5f * (l - r) / den_x : 0.0f;
        const float dy = (den_y != 0.0f) ? 0.5f * (u - d) / den_y : 0.0f;

        out[map * 2 + 0] = (float)x + dx;
        out[map * 2 + 1] = (float)y + dy;
    }
}

extern "C" void kernel_launch(void* const* d_in, const int* in_sizes, int n_in,
                              void* d_out, int out_size, void* d_ws, size_t ws_size,
                              hipStream_t stream) {
    const float* in = (const float*)d_in[0];
    float* out = (float*)d_out;
    const int n_maps = in_sizes[0] / MAP_ELEMS;  // B*N = 2048
    spatial_argmax2d_kernel<<<n_maps, BLOCK, 0, stream>>>(in, out);
}